// Round 4
// baseline (302.660 us; speedup 1.0000x reference)
//
#include <hip/hip_runtime.h>

static inline int ceil_div(int a, int b){ return (a+b-1)/b; }
static inline size_t align_up(size_t x, size_t a){ return (x + a - 1) / a * a; }

typedef __bf16 bf16x8 __attribute__((ext_vector_type(8)));
typedef float  f32x4  __attribute__((ext_vector_type(4)));

static __device__ inline unsigned short f2bf(float f){
    unsigned int u = __float_as_uint(f);
    unsigned int lsb = (u >> 16) & 1u;
    u += 0x7FFFu + lsb;
    return (unsigned short)(u >> 16);
}
static __device__ inline float bf2f(unsigned short b){
    return __uint_as_float(((unsigned int)b) << 16);
}
static __device__ inline unsigned int packbf(float a, float b){
    return (unsigned int)f2bf(a) | ((unsigned int)f2bf(b) << 16);
}

// Bt[o][kk] bf16: kk<1024 -> W[r=kk>>7][i=kk&127][o]; kk>=1024 -> root[kk-1024][o]
__global__ void compute_Bt_kernel(const float* __restrict__ comp, const float* __restrict__ basis,
                                  const float* __restrict__ root, unsigned short* __restrict__ Bt,
                                  int B) {
    int idx = blockIdx.x*blockDim.x + threadIdx.x;
    if (idx >= 128*1152) return;
    int o = idx / 1152, kk = idx - o*1152;
    float val;
    if (kk < 1024) {
        int r = kk >> 7, i = kk & 127;
        val = 0.f;
        for (int b = 0; b < B; ++b)
            val += comp[r*B+b] * basis[((size_t)b*128 + i)*128 + o];
    } else {
        val = root[(size_t)(kk-1024)*128 + o];
    }
    Bt[idx] = f2bf(val);
}

__global__ void count_kernel(const int* __restrict__ dst, const int* __restrict__ et,
                             int* __restrict__ cnt, int E, int R) {
    int e = blockIdx.x*blockDim.x + threadIdx.x;
    if (e >= E) return;
    atomicAdd(&cnt[(size_t)dst[e]*R + et[e]], 1);
}

__global__ __launch_bounds__(256)
void scan_block_kernel(const int* __restrict__ in, int* __restrict__ out,
                       int* __restrict__ bsums, int n) {
    __shared__ int tsum[256];
    int t = threadIdx.x;
    int idx0 = blockIdx.x*1024 + t*4;
    int v0 = (idx0+0 < n) ? in[idx0+0] : 0;
    int v1 = (idx0+1 < n) ? in[idx0+1] : 0;
    int v2 = (idx0+2 < n) ? in[idx0+2] : 0;
    int v3 = (idx0+3 < n) ? in[idx0+3] : 0;
    int s = v0+v1+v2+v3;
    tsum[t] = s; __syncthreads();
    for (int off = 1; off < 256; off <<= 1) {
        int x = (t >= off) ? tsum[t-off] : 0;
        __syncthreads();
        tsum[t] += x;
        __syncthreads();
    }
    int run = tsum[t] - s;
    if (idx0+0 < n) out[idx0+0] = run; run += v0;
    if (idx0+1 < n) out[idx0+1] = run; run += v1;
    if (idx0+2 < n) out[idx0+2] = run; run += v2;
    if (idx0+3 < n) out[idx0+3] = run;
    if (bsums && t == 255) bsums[blockIdx.x] = tsum[255];
}

__global__ void scan_add_kernel(int* __restrict__ out, const int* __restrict__ bs,
                                int n, int total) {
    int i = blockIdx.x*blockDim.x + threadIdx.x;
    if (i < n) out[i] += bs[i >> 10];
    if (i == 0) out[n] = total;
}

__global__ void fill_kernel(const int* __restrict__ src, const int* __restrict__ dst,
                            const int* __restrict__ et, const int* __restrict__ offsets,
                            int* __restrict__ cursor, int* __restrict__ slot_src,
                            int E, int R) {
    int e = blockIdx.x*blockDim.x + threadIdx.x;
    if (e >= E) return;
    int bin = dst[e]*R + et[e];
    int slot = offsets[bin] + atomicAdd(&cursor[bin], 1);
    slot_src[slot] = src[e];
}

// x (f32) -> bf16 pairs into Mc u32 slots 512..575 of each 576-u32 row
__global__ __launch_bounds__(256)
void xb_kernel(const float* __restrict__ x, unsigned int* __restrict__ Mc, int N) {
    int t = blockIdx.x*blockDim.x + threadIdx.x;
    int n = t >> 6;
    if (n >= N) return;
    int l = t & 63;
    float2 v = reinterpret_cast<const float2*>(x + (size_t)n*128)[l];
    Mc[(size_t)n*576 + 512 + l] = packbf(v.x, v.y);
}

// One wave per node: flattened edge loop, 8 named accumulators (R==8),
// relation id = wave-uniform compare-sum. Writes means to Mc slots 0..511.
__global__ __launch_bounds__(256)
void aggregate_kernel(const int* __restrict__ offsets, const int* __restrict__ slot_src,
                      unsigned int* __restrict__ Mc, int N) {
    int w = (int)((blockIdx.x*blockDim.x + threadIdx.x) >> 6);
    if (w >= N) return;
    int l = threadIdx.x & 63;
    const int base = w*8;
    int b0 = offsets[base+0], b1 = offsets[base+1], b2 = offsets[base+2];
    int b3 = offsets[base+3], b4 = offsets[base+4], b5 = offsets[base+5];
    int b6 = offsets[base+6], b7 = offsets[base+7], b8 = offsets[base+8];
    float ax0=0,ax1=0,ax2=0,ax3=0,ax4=0,ax5=0,ax6=0,ax7=0;
    float ay0=0,ay1=0,ay2=0,ay3=0,ay4=0,ay5=0,ay6=0,ay7=0;
    for (int e = b0; e < b8; ++e) {
        int s = slot_src[e];
        unsigned int u = Mc[(size_t)s*576 + 512 + l];
        float vx = bf2f((unsigned short)(u & 0xFFFFu));
        float vy = bf2f((unsigned short)(u >> 16));
        int r = (e>=b1)+(e>=b2)+(e>=b3)+(e>=b4)+(e>=b5)+(e>=b6)+(e>=b7);
        switch (r) {
            case 0: ax0+=vx; ay0+=vy; break;
            case 1: ax1+=vx; ay1+=vy; break;
            case 2: ax2+=vx; ay2+=vy; break;
            case 3: ax3+=vx; ay3+=vy; break;
            case 4: ax4+=vx; ay4+=vy; break;
            case 5: ax5+=vx; ay5+=vy; break;
            case 6: ax6+=vx; ay6+=vy; break;
            default: ax7+=vx; ay7+=vy; break;
        }
    }
    unsigned int* Mrow = Mc + (size_t)w*576;
    float i0 = 1.f/fmaxf((float)(b1-b0),1.f); Mrow[0*64+l] = packbf(ax0*i0, ay0*i0);
    float i1 = 1.f/fmaxf((float)(b2-b1),1.f); Mrow[1*64+l] = packbf(ax1*i1, ay1*i1);
    float i2 = 1.f/fmaxf((float)(b3-b2),1.f); Mrow[2*64+l] = packbf(ax2*i2, ay2*i2);
    float i3 = 1.f/fmaxf((float)(b4-b3),1.f); Mrow[3*64+l] = packbf(ax3*i3, ay3*i3);
    float i4 = 1.f/fmaxf((float)(b5-b4),1.f); Mrow[4*64+l] = packbf(ax4*i4, ay4*i4);
    float i5 = 1.f/fmaxf((float)(b6-b5),1.f); Mrow[5*64+l] = packbf(ax5*i5, ay5*i5);
    float i6 = 1.f/fmaxf((float)(b7-b6),1.f); Mrow[6*64+l] = packbf(ax6*i6, ay6*i6);
    float i7 = 1.f/fmaxf((float)(b8-b7),1.f); Mrow[7*64+l] = packbf(ax7*i7, ay7*i7);
}

// h(bf16)[M,128] = relu( A(bf16)[M,1152] @ Bt^T + bias )
// grid (2, ceil(M/128)): blockIdx.x = col half (fastest -> adjacent blocks share A rows).
// Wave = 32 rows x 64 cols; K-step 64 with distance-1 register prefetch.
__global__ __launch_bounds__(256)
void mfma_gemm_kernel(const unsigned short* __restrict__ Ac,
                      const unsigned short* __restrict__ Btc,
                      const float* __restrict__ bias,
                      unsigned short* __restrict__ h, int M) {
    constexpr int KA = 1152;
    constexpr int NIT = KA/64;       // 18
    int lane = threadIdx.x & 63;
    int wid  = threadIdx.x >> 6;
    int fr = lane & 15, kb = lane >> 4;
    int colbase = blockIdx.x * 64;
    long m0 = (long)blockIdx.y*128 + wid*32;

    const bf16x8* ap0 = reinterpret_cast<const bf16x8*>(Ac + (size_t)(m0 + fr)*KA + kb*8);
    const bf16x8* ap1 = reinterpret_cast<const bf16x8*>(Ac + (size_t)(m0 + 16 + fr)*KA + kb*8);
    const bf16x8* bp  = reinterpret_cast<const bf16x8*>(Btc + (size_t)(colbase + fr)*KA + kb*8);
    const size_t bstride = (size_t)16*(KA/8);   // bf16x8 units per +16 cols

    f32x4 acc[2][4];
    #pragma unroll
    for (int mf = 0; mf < 2; ++mf)
        #pragma unroll
        for (int nf = 0; nf < 4; ++nf) acc[mf][nf] = f32x4{0.f,0.f,0.f,0.f};

    bf16x8 a[2][2], b[4][2];
    #pragma unroll
    for (int j = 0; j < 2; ++j) {
        a[0][j] = ap0[j*4];
        a[1][j] = ap1[j*4];
        #pragma unroll
        for (int nf = 0; nf < 4; ++nf) b[nf][j] = bp[nf*bstride + j*4];
    }

    for (int it = 0; it < NIT; ++it) {
        bf16x8 na[2][2], nb[4][2];
        if (it + 1 < NIT) {
            int o = (it+1)*8;
            #pragma unroll
            for (int j = 0; j < 2; ++j) {
                na[0][j] = ap0[o + j*4];
                na[1][j] = ap1[o + j*4];
                #pragma unroll
                for (int nf = 0; nf < 4; ++nf) nb[nf][j] = bp[nf*bstride + o + j*4];
            }
        }
        #pragma unroll
        for (int j = 0; j < 2; ++j)
            #pragma unroll
            for (int nf = 0; nf < 4; ++nf) {
                acc[0][nf] = __builtin_amdgcn_mfma_f32_16x16x32_bf16(a[0][j], b[nf][j], acc[0][nf], 0, 0, 0);
                acc[1][nf] = __builtin_amdgcn_mfma_f32_16x16x32_bf16(a[1][j], b[nf][j], acc[1][nf], 0, 0, 0);
            }
        #pragma unroll
        for (int j = 0; j < 2; ++j) {
            a[0][j] = na[0][j]; a[1][j] = na[1][j];
            #pragma unroll
            for (int nf = 0; nf < 4; ++nf) b[nf][j] = nb[nf][j];
        }
    }

    float bb[4];
    #pragma unroll
    for (int nf = 0; nf < 4; ++nf) bb[nf] = bias[colbase + nf*16 + fr];

    #pragma unroll
    for (int mf = 0; mf < 2; ++mf)
        #pragma unroll
        for (int q = 0; q < 4; ++q) {
            long r = m0 + mf*16 + kb*4 + q;
            if (r >= M) continue;
            unsigned short* hr = h + (size_t)r*128 + colbase;
            #pragma unroll
            for (int nf = 0; nf < 4; ++nf)
                hr[nf*16 + fr] = f2bf(fmaxf(acc[mf][nf][q] + bb[nf], 0.f));
        }
}

// Fused: per-graph row-range (binary search on sorted batch) -> mean pool -> FC.
__global__ __launch_bounds__(512)
void pool_fc_kernel(const unsigned int* __restrict__ h2, const int* __restrict__ batch,
                    const float* __restrict__ fw, const float* __restrict__ fb,
                    float* __restrict__ out, int N, int C) {
    int g = blockIdx.x;
    int t = threadIdx.x;
    int lo = 0, hi = N;
    while (lo < hi) { int mid = (lo+hi) >> 1; if (batch[mid] < g) lo = mid+1; else hi = mid; }
    int s0 = lo;
    hi = N;
    while (lo < hi) { int mid = (lo+hi) >> 1; if (batch[mid] < g+1) lo = mid+1; else hi = mid; }
    int s1 = lo;

    int d2 = t & 63;
    float ax = 0.f, ay = 0.f;
    for (int row = s0 + (t >> 6); row < s1; row += 8) {
        unsigned int u = h2[(size_t)row*64 + d2];
        ax += bf2f((unsigned short)(u & 0xFFFFu));
        ay += bf2f((unsigned short)(u >> 16));
    }
    __shared__ float ps[128];
    if (t < 128) ps[t] = 0.f;
    __syncthreads();
    atomicAdd(&ps[2*d2],   ax);
    atomicAdd(&ps[2*d2+1], ay);
    __syncthreads();
    if (t < C) {
        float inv = 1.f / fmaxf((float)(s1 - s0), 1.f);
        float s = 0.f;
        #pragma unroll 4
        for (int k = 0; k < 128; ++k) s += ps[k] * fw[(size_t)k*C + t];
        out[(size_t)g*C + t] = s * inv + fb[t];
    }
}

extern "C" void kernel_launch(void* const* d_in, const int* in_sizes, int n_in,
                              void* d_out, int out_size, void* d_ws, size_t ws_size,
                              hipStream_t stream) {
    const float* x       = (const float*)d_in[0];
    const int*   eindex  = (const int*)  d_in[1];
    const int*   etype   = (const int*)  d_in[2];
    const int*   batch   = (const int*)  d_in[4];
    const float* basis   = (const float*)d_in[6];
    const float* comp    = (const float*)d_in[7];
    const float* root    = (const float*)d_in[8];
    const float* bias    = (const float*)d_in[9];
    const float* fc_w    = (const float*)d_in[10];
    const float* fc_b    = (const float*)d_in[11];

    int N  = in_sizes[4];          // 50000
    int E  = in_sizes[2];          // 600000
    int C  = in_sizes[11];         // 16
    int G  = out_size / C;         // 64
    int IO = in_sizes[8];          // 16384
    int B  = in_sizes[6] / IO;     // 4
    int R  = in_sizes[7] / B;      // 8
    int NR = N * R;
    int MB = ceil_div(N, 128);     // row blocks
    int Mpad = MB * 128;

    const int* src = eindex;
    const int* dst = eindex + E;

    // ---- workspace layout ----
    char* base = (char*)d_ws;
    size_t off = 0;
    auto alloc = [&](size_t bytes) -> char* {
        char* p = base + off;
        off = align_up(off + bytes, 256);
        return p;
    };
    unsigned short* Bt  = (unsigned short*)alloc(sizeof(unsigned short)*128*1152);
    int*   cnt      = (int*)  alloc(sizeof(int)*(size_t)NR);          // also cursor
    int*   offsets  = (int*)  alloc(sizeof(int)*((size_t)NR+1));
    int*   bsums    = (int*)  alloc(sizeof(int)*1024);
    int*   slot_src = (int*)  alloc(sizeof(int)*(size_t)E);
    unsigned short* h = (unsigned short*)alloc(sizeof(unsigned short)*(size_t)Mpad*128);
    unsigned int* Mc = (unsigned int*)alloc(sizeof(unsigned short)*(size_t)Mpad*1152);

    // ---- pipeline ----
    hipMemsetAsync(cnt, 0, sizeof(int)*(size_t)NR, stream);
    compute_Bt_kernel<<<ceil_div(128*1152,256),256,0,stream>>>(comp, basis, root, Bt, B);
    count_kernel<<<ceil_div(E,256),256,0,stream>>>(dst, etype, cnt, E, R);

    int nb = ceil_div(NR, 1024);
    scan_block_kernel<<<nb,256,0,stream>>>(cnt, offsets, bsums, NR);
    scan_block_kernel<<<1,256,0,stream>>>(bsums, bsums, nullptr, nb);
    scan_add_kernel<<<ceil_div(NR,256),256,0,stream>>>(offsets, bsums, NR, E);

    hipMemsetAsync(cnt, 0, sizeof(int)*(size_t)NR, stream);  // reuse as cursor
    fill_kernel<<<ceil_div(E,256),256,0,stream>>>(src, dst, etype, offsets, cnt, slot_src, E, R);

    xb_kernel<<<ceil_div(N*64,256),256,0,stream>>>(x, Mc, N);
    aggregate_kernel<<<ceil_div(N*64,256),256,0,stream>>>(offsets, slot_src, Mc, N);

    mfma_gemm_kernel<<<dim3(2, MB),256,0,stream>>>((const unsigned short*)Mc, Bt, bias, h, N);

    pool_fc_kernel<<<G,512,0,stream>>>((const unsigned int*)h, batch, fc_w, fc_b,
                                       (float*)d_out, N, C);
}

// Round 5
// 287.609 us; speedup vs baseline: 1.0523x; 1.0523x over previous
//
#include <hip/hip_runtime.h>

static inline int ceil_div(int a, int b){ return (a+b-1)/b; }
static inline size_t align_up(size_t x, size_t a){ return (x + a - 1) / a * a; }

typedef __bf16 bf16x8 __attribute__((ext_vector_type(8)));
typedef float  f32x4  __attribute__((ext_vector_type(4)));

static __device__ inline unsigned short f2bf(float f){
    unsigned int u = __float_as_uint(f);
    unsigned int lsb = (u >> 16) & 1u;
    u += 0x7FFFu + lsb;
    return (unsigned short)(u >> 16);
}
static __device__ inline float bf2f(unsigned short b){
    return __uint_as_float(((unsigned int)b) << 16);
}
static __device__ inline unsigned int packbf(float a, float b){
    return (unsigned int)f2bf(a) | ((unsigned int)f2bf(b) << 16);
}

// Bt[o][kk] bf16: kk<1024 -> W[r=kk>>7][i=kk&127][o]; kk>=1024 -> root[kk-1024][o]
__global__ void compute_Bt_kernel(const float* __restrict__ comp, const float* __restrict__ basis,
                                  const float* __restrict__ root, unsigned short* __restrict__ Bt,
                                  int B) {
    int idx = blockIdx.x*blockDim.x + threadIdx.x;
    if (idx >= 128*1152) return;
    int o = idx / 1152, kk = idx - o*1152;
    float val;
    if (kk < 1024) {
        int r = kk >> 7, i = kk & 127;
        val = 0.f;
        for (int b = 0; b < B; ++b)
            val += comp[r*B+b] * basis[((size_t)b*128 + i)*128 + o];
    } else {
        val = root[(size_t)(kk-1024)*128 + o];
    }
    Bt[idx] = f2bf(val);
}

__global__ void count_kernel(const int* __restrict__ dst, const int* __restrict__ et,
                             int* __restrict__ cnt, int E, int R) {
    int e = blockIdx.x*blockDim.x + threadIdx.x;
    if (e >= E) return;
    atomicAdd(&cnt[(size_t)dst[e]*R + et[e]], 1);
}

__global__ __launch_bounds__(256)
void scan_block_kernel(const int* __restrict__ in, int* __restrict__ out,
                       int* __restrict__ bsums, int n) {
    __shared__ int tsum[256];
    int t = threadIdx.x;
    int idx0 = blockIdx.x*1024 + t*4;
    int v0 = (idx0+0 < n) ? in[idx0+0] : 0;
    int v1 = (idx0+1 < n) ? in[idx0+1] : 0;
    int v2 = (idx0+2 < n) ? in[idx0+2] : 0;
    int v3 = (idx0+3 < n) ? in[idx0+3] : 0;
    int s = v0+v1+v2+v3;
    tsum[t] = s; __syncthreads();
    for (int off = 1; off < 256; off <<= 1) {
        int x = (t >= off) ? tsum[t-off] : 0;
        __syncthreads();
        tsum[t] += x;
        __syncthreads();
    }
    int run = tsum[t] - s;
    if (idx0+0 < n) out[idx0+0] = run; run += v0;
    if (idx0+1 < n) out[idx0+1] = run; run += v1;
    if (idx0+2 < n) out[idx0+2] = run; run += v2;
    if (idx0+3 < n) out[idx0+3] = run;
    if (bsums && t == 255) bsums[blockIdx.x] = tsum[255];
}

__global__ void scan_add_kernel(int* __restrict__ out, const int* __restrict__ bs,
                                int n, int total) {
    int i = blockIdx.x*blockDim.x + threadIdx.x;
    if (i < n) out[i] += bs[i >> 10];
    if (i == 0) out[n] = total;
}

// slot = atomicAdd(&offsets[bin],1): offsets mutates into shifted-by-one bounds.
__global__ void fill_kernel(const int* __restrict__ src, const int* __restrict__ dst,
                            const int* __restrict__ et, int* __restrict__ offsets,
                            int* __restrict__ slot_src, int E, int R) {
    int e = blockIdx.x*blockDim.x + threadIdx.x;
    if (e >= E) return;
    int bin = dst[e]*R + et[e];
    int slot = atomicAdd(&offsets[bin], 1);
    slot_src[slot] = src[e];
}

// x (f32) -> bf16 pairs into Mc u32 slots 512..575 of each 576-u32 row
__global__ __launch_bounds__(256)
void xb_kernel(const float* __restrict__ x, unsigned int* __restrict__ Mc, int N) {
    int t = blockIdx.x*blockDim.x + threadIdx.x;
    int n = t >> 6;
    if (n >= N) return;
    int l = t & 63;
    float2 v = reinterpret_cast<const float2*>(x + (size_t)n*128)[l];
    Mc[(size_t)n*576 + 512 + l] = packbf(v.x, v.y);
}

// One wave per node. Post-fill offsets convention: bin b = [off[b-1], off[b]) with off[-1]=0.
__global__ __launch_bounds__(256)
void aggregate_kernel(const int* __restrict__ offsets, const int* __restrict__ slot_src,
                      unsigned int* __restrict__ Mc, int N) {
    int w = (int)((blockIdx.x*blockDim.x + threadIdx.x) >> 6);
    if (w >= N) return;
    int l = threadIdx.x & 63;
    const int base = w*8;
    int b0 = (w == 0) ? 0 : offsets[base-1];
    int b1 = offsets[base+0], b2 = offsets[base+1], b3 = offsets[base+2];
    int b4 = offsets[base+3], b5 = offsets[base+4], b6 = offsets[base+5];
    int b7 = offsets[base+6], b8 = offsets[base+7];
    float ax0=0,ax1=0,ax2=0,ax3=0,ax4=0,ax5=0,ax6=0,ax7=0;
    float ay0=0,ay1=0,ay2=0,ay3=0,ay4=0,ay5=0,ay6=0,ay7=0;
    for (int e = b0; e < b8; ++e) {
        int s = slot_src[e];
        unsigned int u = Mc[(size_t)s*576 + 512 + l];
        float vx = bf2f((unsigned short)(u & 0xFFFFu));
        float vy = bf2f((unsigned short)(u >> 16));
        int r = (e>=b1)+(e>=b2)+(e>=b3)+(e>=b4)+(e>=b5)+(e>=b6)+(e>=b7);
        switch (r) {
            case 0: ax0+=vx; ay0+=vy; break;
            case 1: ax1+=vx; ay1+=vy; break;
            case 2: ax2+=vx; ay2+=vy; break;
            case 3: ax3+=vx; ay3+=vy; break;
            case 4: ax4+=vx; ay4+=vy; break;
            case 5: ax5+=vx; ay5+=vy; break;
            case 6: ax6+=vx; ay6+=vy; break;
            default: ax7+=vx; ay7+=vy; break;
        }
    }
    unsigned int* Mrow = Mc + (size_t)w*576;
    float i0 = 1.f/fmaxf((float)(b1-b0),1.f); Mrow[0*64+l] = packbf(ax0*i0, ay0*i0);
    float i1 = 1.f/fmaxf((float)(b2-b1),1.f); Mrow[1*64+l] = packbf(ax1*i1, ay1*i1);
    float i2 = 1.f/fmaxf((float)(b3-b2),1.f); Mrow[2*64+l] = packbf(ax2*i2, ay2*i2);
    float i3 = 1.f/fmaxf((float)(b4-b3),1.f); Mrow[3*64+l] = packbf(ax3*i3, ay3*i3);
    float i4 = 1.f/fmaxf((float)(b5-b4),1.f); Mrow[4*64+l] = packbf(ax4*i4, ay4*i4);
    float i5 = 1.f/fmaxf((float)(b6-b5),1.f); Mrow[5*64+l] = packbf(ax5*i5, ay5*i5);
    float i6 = 1.f/fmaxf((float)(b7-b6),1.f); Mrow[6*64+l] = packbf(ax6*i6, ay6*i6);
    float i7 = 1.f/fmaxf((float)(b8-b7),1.f); Mrow[7*64+l] = packbf(ax7*i7, ay7*i7);
}

// h(bf16)[M,128] = relu( A(bf16)[M,1152] @ Bt^T + bias )
// Block = 4 waves: (rg = wid&1) 32-row group, (kh = wid>>1) K-half of 576.
// K-halves combined via LDS. Grid = ceil(M/64). B ping-pong prefetch, A depth-2.
__global__ __launch_bounds__(256, 3)
void mfma_gemm_kernel(const unsigned short* __restrict__ Ac,
                      const unsigned short* __restrict__ Btc,
                      const float* __restrict__ bias,
                      unsigned short* __restrict__ h, int M) {
    constexpr int KA = 1152;
    constexpr int RSTR = KA/8;        // bf16x8 units per row = 144
    __shared__ float red[2][32][128];
    int lane = threadIdx.x & 63;
    int wid  = threadIdx.x >> 6;
    int rg = wid & 1, kh = wid >> 1;
    int fr = lane & 15, kb = lane >> 4;
    long m0 = (long)blockIdx.x*64 + rg*32;

    const bf16x8* ap0 = reinterpret_cast<const bf16x8*>(Ac) + (size_t)(m0 + fr)*RSTR      + kh*72 + kb;
    const bf16x8* ap1 = reinterpret_cast<const bf16x8*>(Ac) + (size_t)(m0 + 16 + fr)*RSTR + kh*72 + kb;
    const bf16x8* bp  = reinterpret_cast<const bf16x8*>(Btc) + (size_t)fr*RSTR            + kh*72 + kb;
    constexpr size_t BS = (size_t)16*RSTR;   // +16 output cols

    f32x4 acc[2][8];
    #pragma unroll
    for (int mf = 0; mf < 2; ++mf)
        #pragma unroll
        for (int nf = 0; nf < 8; ++nf) acc[mf][nf] = f32x4{0.f,0.f,0.f,0.f};

    // slots X (even step), Y (odd step); 18 K-steps of 32
    bf16x8 aX0 = ap0[0], aX1 = ap1[0];
    bf16x8 aY0 = ap0[4], aY1 = ap1[4];
    bf16x8 bX[8], bY[8];
    #pragma unroll
    for (int nf = 0; nf < 8; ++nf) { bX[nf] = bp[nf*BS]; bY[nf] = bp[nf*BS + 4]; }

    for (int s = 0; s < 16; s += 2) {
        {
            bf16x8 ta0 = ap0[(s+2)*4], ta1 = ap1[(s+2)*4];
            bf16x8 tb[8];
            #pragma unroll
            for (int nf = 0; nf < 8; ++nf) tb[nf] = bp[nf*BS + (s+2)*4];
            #pragma unroll
            for (int nf = 0; nf < 8; ++nf) {
                acc[0][nf] = __builtin_amdgcn_mfma_f32_16x16x32_bf16(aX0, bX[nf], acc[0][nf], 0, 0, 0);
                acc[1][nf] = __builtin_amdgcn_mfma_f32_16x16x32_bf16(aX1, bX[nf], acc[1][nf], 0, 0, 0);
            }
            aX0 = ta0; aX1 = ta1;
            #pragma unroll
            for (int nf = 0; nf < 8; ++nf) bX[nf] = tb[nf];
        }
        {
            bf16x8 ta0 = ap0[(s+3)*4], ta1 = ap1[(s+3)*4];
            bf16x8 tb[8];
            #pragma unroll
            for (int nf = 0; nf < 8; ++nf) tb[nf] = bp[nf*BS + (s+3)*4];
            #pragma unroll
            for (int nf = 0; nf < 8; ++nf) {
                acc[0][nf] = __builtin_amdgcn_mfma_f32_16x16x32_bf16(aY0, bY[nf], acc[0][nf], 0, 0, 0);
                acc[1][nf] = __builtin_amdgcn_mfma_f32_16x16x32_bf16(aY1, bY[nf], acc[1][nf], 0, 0, 0);
            }
            aY0 = ta0; aY1 = ta1;
            #pragma unroll
            for (int nf = 0; nf < 8; ++nf) bY[nf] = tb[nf];
        }
    }
    #pragma unroll
    for (int nf = 0; nf < 8; ++nf) {
        acc[0][nf] = __builtin_amdgcn_mfma_f32_16x16x32_bf16(aX0, bX[nf], acc[0][nf], 0, 0, 0);
        acc[1][nf] = __builtin_amdgcn_mfma_f32_16x16x32_bf16(aX1, bX[nf], acc[1][nf], 0, 0, 0);
    }
    #pragma unroll
    for (int nf = 0; nf < 8; ++nf) {
        acc[0][nf] = __builtin_amdgcn_mfma_f32_16x16x32_bf16(aY0, bY[nf], acc[0][nf], 0, 0, 0);
        acc[1][nf] = __builtin_amdgcn_mfma_f32_16x16x32_bf16(aY1, bY[nf], acc[1][nf], 0, 0, 0);
    }

    // kh=1 waves deposit partials in LDS
    if (kh == 1) {
        #pragma unroll
        for (int mf = 0; mf < 2; ++mf)
            #pragma unroll
            for (int q = 0; q < 4; ++q)
                #pragma unroll
                for (int nf = 0; nf < 8; ++nf)
                    red[rg][mf*16 + kb*4 + q][nf*16 + fr] = acc[mf][nf][q];
    }
    __syncthreads();
    if (kh == 0) {
        float bb[8];
        #pragma unroll
        for (int nf = 0; nf < 8; ++nf) bb[nf] = bias[nf*16 + fr];
        #pragma unroll
        for (int mf = 0; mf < 2; ++mf)
            #pragma unroll
            for (int q = 0; q < 4; ++q) {
                long r = m0 + mf*16 + kb*4 + q;
                if (r >= M) continue;
                unsigned short* hr = h + (size_t)r*128;
                #pragma unroll
                for (int nf = 0; nf < 8; ++nf) {
                    float v = acc[mf][nf][q] + red[rg][mf*16 + kb*4 + q][nf*16 + fr] + bb[nf];
                    hr[nf*16 + fr] = f2bf(fmaxf(v, 0.f));
                }
            }
    }
}

// Fused: per-graph row-range (binary search on sorted batch) -> mean pool -> FC.
__global__ __launch_bounds__(512)
void pool_fc_kernel(const unsigned int* __restrict__ h2, const int* __restrict__ batch,
                    const float* __restrict__ fw, const float* __restrict__ fb,
                    float* __restrict__ out, int N, int C) {
    int g = blockIdx.x;
    int t = threadIdx.x;
    int lo = 0, hi = N;
    while (lo < hi) { int mid = (lo+hi) >> 1; if (batch[mid] < g) lo = mid+1; else hi = mid; }
    int s0 = lo;
    hi = N;
    while (lo < hi) { int mid = (lo+hi) >> 1; if (batch[mid] < g+1) lo = mid+1; else hi = mid; }
    int s1 = lo;

    int d2 = t & 63;
    float ax = 0.f, ay = 0.f;
    for (int row = s0 + (t >> 6); row < s1; row += 8) {
        unsigned int u = h2[(size_t)row*64 + d2];
        ax += bf2f((unsigned short)(u & 0xFFFFu));
        ay += bf2f((unsigned short)(u >> 16));
    }
    __shared__ float ps[128];
    if (t < 128) ps[t] = 0.f;
    __syncthreads();
    atomicAdd(&ps[2*d2],   ax);
    atomicAdd(&ps[2*d2+1], ay);
    __syncthreads();
    if (t < C) {
        float inv = 1.f / fmaxf((float)(s1 - s0), 1.f);
        float s = 0.f;
        #pragma unroll 4
        for (int k = 0; k < 128; ++k) s += ps[k] * fw[(size_t)k*C + t];
        out[(size_t)g*C + t] = s * inv + fb[t];
    }
}

extern "C" void kernel_launch(void* const* d_in, const int* in_sizes, int n_in,
                              void* d_out, int out_size, void* d_ws, size_t ws_size,
                              hipStream_t stream) {
    const float* x       = (const float*)d_in[0];
    const int*   eindex  = (const int*)  d_in[1];
    const int*   etype   = (const int*)  d_in[2];
    const int*   batch   = (const int*)  d_in[4];
    const float* basis   = (const float*)d_in[6];
    const float* comp    = (const float*)d_in[7];
    const float* root    = (const float*)d_in[8];
    const float* bias    = (const float*)d_in[9];
    const float* fc_w    = (const float*)d_in[10];
    const float* fc_b    = (const float*)d_in[11];

    int N  = in_sizes[4];          // 50000
    int E  = in_sizes[2];          // 600000
    int C  = in_sizes[11];         // 16
    int G  = out_size / C;         // 64
    int IO = in_sizes[8];          // 16384
    int B  = in_sizes[6] / IO;     // 4
    int R  = in_sizes[7] / B;      // 8
    int NR = N * R;
    int MB = ceil_div(N, 64);      // 64-row GEMM blocks
    int Mpad = MB * 64;

    const int* src = eindex;
    const int* dst = eindex + E;

    // ---- workspace layout ----
    char* base = (char*)d_ws;
    size_t off = 0;
    auto alloc = [&](size_t bytes) -> char* {
        char* p = base + off;
        off = align_up(off + bytes, 256);
        return p;
    };
    unsigned short* Bt  = (unsigned short*)alloc(sizeof(unsigned short)*128*1152);
    int*   cnt      = (int*)  alloc(sizeof(int)*(size_t)NR);
    int*   offsets  = (int*)  alloc(sizeof(int)*((size_t)NR+1));
    int*   bsums    = (int*)  alloc(sizeof(int)*1024);
    int*   slot_src = (int*)  alloc(sizeof(int)*(size_t)E);
    unsigned short* h = (unsigned short*)alloc(sizeof(unsigned short)*(size_t)Mpad*128);
    unsigned int* Mc = (unsigned int*)alloc(sizeof(unsigned short)*(size_t)Mpad*1152);

    // ---- pipeline ----
    hipMemsetAsync(cnt, 0, sizeof(int)*(size_t)NR, stream);
    compute_Bt_kernel<<<ceil_div(128*1152,256),256,0,stream>>>(comp, basis, root, Bt, B);
    count_kernel<<<ceil_div(E,256),256,0,stream>>>(dst, etype, cnt, E, R);

    int nb = ceil_div(NR, 1024);
    scan_block_kernel<<<nb,256,0,stream>>>(cnt, offsets, bsums, NR);
    scan_block_kernel<<<1,256,0,stream>>>(bsums, bsums, nullptr, nb);
    scan_add_kernel<<<ceil_div(NR,256),256,0,stream>>>(offsets, bsums, NR, E);

    fill_kernel<<<ceil_div(E,256),256,0,stream>>>(src, dst, etype, offsets, slot_src, E, R);

    xb_kernel<<<ceil_div(N*64,256),256,0,stream>>>(x, Mc, N);
    aggregate_kernel<<<ceil_div(N*64,256),256,0,stream>>>(offsets, slot_src, Mc, N);

    mfma_gemm_kernel<<<MB,256,0,stream>>>((const unsigned short*)Mc, Bt, bias, h, N);

    pool_fc_kernel<<<G,512,0,stream>>>((const unsigned int*)h, batch, fc_w, fc_b,
                                       (float*)d_out, N, C);
}

// Round 6
// 284.342 us; speedup vs baseline: 1.0644x; 1.0115x over previous
//
#include <hip/hip_runtime.h>

static inline int ceil_div(int a, int b){ return (a+b-1)/b; }
static inline size_t align_up(size_t x, size_t a){ return (x + a - 1) / a * a; }

typedef __bf16 bf16x8 __attribute__((ext_vector_type(8)));
typedef float  f32x4  __attribute__((ext_vector_type(4)));

static __device__ inline unsigned short f2bf(float f){
    unsigned int u = __float_as_uint(f);
    unsigned int lsb = (u >> 16) & 1u;
    u += 0x7FFFu + lsb;
    return (unsigned short)(u >> 16);
}
static __device__ inline float bf2f(unsigned short b){
    return __uint_as_float(((unsigned int)b) << 16);
}
static __device__ inline unsigned int packbf(float a, float b){
    return (unsigned int)f2bf(a) | ((unsigned int)f2bf(b) << 16);
}

// Bt[o][kk] bf16: kk<1024 -> W[r=kk>>7][i=kk&127][o]; kk>=1024 -> root[kk-1024][o]
__global__ void compute_Bt_kernel(const float* __restrict__ comp, const float* __restrict__ basis,
                                  const float* __restrict__ root, unsigned short* __restrict__ Bt,
                                  int B) {
    int idx = blockIdx.x*blockDim.x + threadIdx.x;
    if (idx >= 128*1152) return;
    int o = idx / 1152, kk = idx - o*1152;
    float val;
    if (kk < 1024) {
        int r = kk >> 7, i = kk & 127;
        val = 0.f;
        for (int b = 0; b < B; ++b)
            val += comp[r*B+b] * basis[((size_t)b*128 + i)*128 + o];
    } else {
        val = root[(size_t)(kk-1024)*128 + o];
    }
    Bt[idx] = f2bf(val);
}

__global__ void count_kernel(const int* __restrict__ dst, const int* __restrict__ et,
                             int* __restrict__ cnt, int E, int R) {
    int e = blockIdx.x*blockDim.x + threadIdx.x;
    if (e >= E) return;
    atomicAdd(&cnt[(size_t)dst[e]*R + et[e]], 1);
}

__global__ __launch_bounds__(256)
void scan_block_kernel(const int* __restrict__ in, int* __restrict__ out,
                       int* __restrict__ bsums, int n) {
    __shared__ int tsum[256];
    int t = threadIdx.x;
    int idx0 = blockIdx.x*1024 + t*4;
    int v0 = (idx0+0 < n) ? in[idx0+0] : 0;
    int v1 = (idx0+1 < n) ? in[idx0+1] : 0;
    int v2 = (idx0+2 < n) ? in[idx0+2] : 0;
    int v3 = (idx0+3 < n) ? in[idx0+3] : 0;
    int s = v0+v1+v2+v3;
    tsum[t] = s; __syncthreads();
    for (int off = 1; off < 256; off <<= 1) {
        int x = (t >= off) ? tsum[t-off] : 0;
        __syncthreads();
        tsum[t] += x;
        __syncthreads();
    }
    int run = tsum[t] - s;
    if (idx0+0 < n) out[idx0+0] = run; run += v0;
    if (idx0+1 < n) out[idx0+1] = run; run += v1;
    if (idx0+2 < n) out[idx0+2] = run; run += v2;
    if (idx0+3 < n) out[idx0+3] = run;
    if (bsums && t == 255) bsums[blockIdx.x] = tsum[255];
}

__global__ void scan_add_kernel(int* __restrict__ out, const int* __restrict__ bs,
                                int n, int total) {
    int i = blockIdx.x*blockDim.x + threadIdx.x;
    if (i < n) out[i] += bs[i >> 10];
    if (i == 0) out[n] = total;
}

// slot = atomicAdd(&offsets[bin],1): offsets mutates into shifted-by-one bounds.
__global__ void fill_kernel(const int* __restrict__ src, const int* __restrict__ dst,
                            const int* __restrict__ et, int* __restrict__ offsets,
                            int* __restrict__ slot_src, int E, int R) {
    int e = blockIdx.x*blockDim.x + threadIdx.x;
    if (e >= E) return;
    int bin = dst[e]*R + et[e];
    int slot = atomicAdd(&offsets[bin], 1);
    slot_src[slot] = src[e];
}

// x (f32) -> compact bf16 buffer Xb [N][128] (u32 pairs)
__global__ __launch_bounds__(256)
void xb_kernel(const float* __restrict__ x, unsigned int* __restrict__ Xb2, int N) {
    int t = blockIdx.x*blockDim.x + threadIdx.x;
    int n = t >> 6;
    if (n >= N) return;
    int l = t & 63;
    float2 v = reinterpret_cast<const float2*>(x + (size_t)n*128)[l];
    Xb2[(size_t)n*64 + l] = packbf(v.x, v.y);
}

// One wave per node; bounds shifted-by-one: bin b = [off[b-1], off[b]), off[-1]=0.
// MLP=4: 4 slot loads + 4 row loads hoisted ahead of the accumulate switches.
__global__ __launch_bounds__(256)
void aggregate_kernel(const int* __restrict__ offsets, const int* __restrict__ slot_src,
                      const unsigned int* __restrict__ Xb2, unsigned int* __restrict__ Mc2,
                      int N) {
    int w = (int)((blockIdx.x*blockDim.x + threadIdx.x) >> 6);
    if (w >= N) return;
    int l = threadIdx.x & 63;
    const int base = w*8;
    int b0 = (w == 0) ? 0 : offsets[base-1];
    int b1 = offsets[base+0], b2 = offsets[base+1], b3 = offsets[base+2];
    int b4 = offsets[base+3], b5 = offsets[base+4], b6 = offsets[base+5];
    int b7 = offsets[base+6], b8 = offsets[base+7];
    float ax0=0,ax1=0,ax2=0,ax3=0,ax4=0,ax5=0,ax6=0,ax7=0;
    float ay0=0,ay1=0,ay2=0,ay3=0,ay4=0,ay5=0,ay6=0,ay7=0;

#define ACCQ(E_, U_) { \
    int r_ = ((E_)>=b1)+((E_)>=b2)+((E_)>=b3)+((E_)>=b4)+((E_)>=b5)+((E_)>=b6)+((E_)>=b7); \
    float vx_ = bf2f((unsigned short)((U_) & 0xFFFFu)); \
    float vy_ = bf2f((unsigned short)((U_) >> 16)); \
    switch (r_) { \
        case 0: ax0+=vx_; ay0+=vy_; break; \
        case 1: ax1+=vx_; ay1+=vy_; break; \
        case 2: ax2+=vx_; ay2+=vy_; break; \
        case 3: ax3+=vx_; ay3+=vy_; break; \
        case 4: ax4+=vx_; ay4+=vy_; break; \
        case 5: ax5+=vx_; ay5+=vy_; break; \
        case 6: ax6+=vx_; ay6+=vy_; break; \
        default: ax7+=vx_; ay7+=vy_; break; \
    } }

    int e = b0;
    for (; e + 4 <= b8; e += 4) {
        int s0 = slot_src[e], s1 = slot_src[e+1], s2 = slot_src[e+2], s3 = slot_src[e+3];
        unsigned int u0 = Xb2[(size_t)s0*64 + l];
        unsigned int u1 = Xb2[(size_t)s1*64 + l];
        unsigned int u2 = Xb2[(size_t)s2*64 + l];
        unsigned int u3 = Xb2[(size_t)s3*64 + l];
        ACCQ(e+0, u0) ACCQ(e+1, u1) ACCQ(e+2, u2) ACCQ(e+3, u3)
    }
    for (; e < b8; ++e) {
        int s = slot_src[e];
        unsigned int u = Xb2[(size_t)s*64 + l];
        ACCQ(e, u)
    }
#undef ACCQ

    unsigned int* Mrow = Mc2 + (size_t)w*512;
    float i0 = 1.f/fmaxf((float)(b1-b0),1.f); Mrow[0*64+l] = packbf(ax0*i0, ay0*i0);
    float i1 = 1.f/fmaxf((float)(b2-b1),1.f); Mrow[1*64+l] = packbf(ax1*i1, ay1*i1);
    float i2 = 1.f/fmaxf((float)(b3-b2),1.f); Mrow[2*64+l] = packbf(ax2*i2, ay2*i2);
    float i3 = 1.f/fmaxf((float)(b4-b3),1.f); Mrow[3*64+l] = packbf(ax3*i3, ay3*i3);
    float i4 = 1.f/fmaxf((float)(b5-b4),1.f); Mrow[4*64+l] = packbf(ax4*i4, ay4*i4);
    float i5 = 1.f/fmaxf((float)(b6-b5),1.f); Mrow[5*64+l] = packbf(ax5*i5, ay5*i5);
    float i6 = 1.f/fmaxf((float)(b7-b6),1.f); Mrow[6*64+l] = packbf(ax6*i6, ay6*i6);
    float i7 = 1.f/fmaxf((float)(b8-b7),1.f); Mrow[7*64+l] = packbf(ax7*i7, ay7*i7);
}

// h(bf16)[Mpad][128] = relu( [Mc | Xb] @ Bt^T + bias )
// Block = 4 waves: rg = wid&1 (32-row group), cg = wid>>1 (64-col group).
// Depth-3 register ring on A and B, fully unrolled 36 K-steps. No LDS.
__global__ __launch_bounds__(256)
void mfma_gemm_kernel(const unsigned short* __restrict__ Mc,
                      const unsigned short* __restrict__ Xb,
                      const unsigned short* __restrict__ Btc,
                      const float* __restrict__ bias,
                      unsigned short* __restrict__ h) {
    int lane = threadIdx.x & 63;
    int wid  = threadIdx.x >> 6;
    int rg = wid & 1, cg = wid >> 1;
    int fr = lane & 15, kb = lane >> 4;
    long m0 = (long)blockIdx.x*64 + rg*32;
    int colbase = cg*64;

    const bf16x8* aM0 = reinterpret_cast<const bf16x8*>(Mc + (size_t)(m0+fr)*1024) + kb;
    const bf16x8* aM1 = reinterpret_cast<const bf16x8*>(Mc + (size_t)(m0+16+fr)*1024) + kb;
    const bf16x8* aX0 = reinterpret_cast<const bf16x8*>(Xb + (size_t)(m0+fr)*128) + kb;
    const bf16x8* aX1 = reinterpret_cast<const bf16x8*>(Xb + (size_t)(m0+16+fr)*128) + kb;
    const bf16x8* bp  = reinterpret_cast<const bf16x8*>(Btc + (size_t)(colbase+fr)*1152) + kb;
    constexpr size_t BS = (size_t)16*144;   // +16 output cols in Bt units

    f32x4 acc[2][4];
    #pragma unroll
    for (int mf = 0; mf < 2; ++mf)
        #pragma unroll
        for (int nf = 0; nf < 4; ++nf) acc[mf][nf] = f32x4{0.f,0.f,0.f,0.f};

    bf16x8 a[3][2], b[3][4];

#define LOADS(SLOT, S) { \
    if ((S) < 32) { a[SLOT][0] = aM0[(S)*4]; a[SLOT][1] = aM1[(S)*4]; } \
    else          { a[SLOT][0] = aX0[((S)-32)*4]; a[SLOT][1] = aX1[((S)-32)*4]; } \
    b[SLOT][0] = bp[0*BS + (S)*4]; b[SLOT][1] = bp[1*BS + (S)*4]; \
    b[SLOT][2] = bp[2*BS + (S)*4]; b[SLOT][3] = bp[3*BS + (S)*4]; }

    LOADS(0,0) LOADS(1,1) LOADS(2,2)

    #pragma unroll
    for (int s = 0; s < 36; ++s) {
        int slot = s % 3;
        #pragma unroll
        for (int nf = 0; nf < 4; ++nf) {
            acc[0][nf] = __builtin_amdgcn_mfma_f32_16x16x32_bf16(a[slot][0], b[slot][nf], acc[0][nf], 0, 0, 0);
            acc[1][nf] = __builtin_amdgcn_mfma_f32_16x16x32_bf16(a[slot][1], b[slot][nf], acc[1][nf], 0, 0, 0);
        }
        if (s + 3 < 36) { LOADS(slot, s+3) }
    }
#undef LOADS

    float bb[4];
    #pragma unroll
    for (int nf = 0; nf < 4; ++nf) bb[nf] = bias[colbase + nf*16 + fr];

    #pragma unroll
    for (int mf = 0; mf < 2; ++mf)
        #pragma unroll
        for (int q = 0; q < 4; ++q) {
            long r = m0 + mf*16 + kb*4 + q;
            unsigned short* hr = h + (size_t)r*128 + colbase;
            #pragma unroll
            for (int nf = 0; nf < 4; ++nf)
                hr[nf*16 + fr] = f2bf(fmaxf(acc[mf][nf][q] + bb[nf], 0.f));
        }
}

// Fused: per-graph row-range (binary search on sorted batch) -> mean pool -> FC.
__global__ __launch_bounds__(512)
void pool_fc_kernel(const unsigned int* __restrict__ h2, const int* __restrict__ batch,
                    const float* __restrict__ fw, const float* __restrict__ fb,
                    float* __restrict__ out, int N, int C) {
    int g = blockIdx.x;
    int t = threadIdx.x;
    int lo = 0, hi = N;
    while (lo < hi) { int mid = (lo+hi) >> 1; if (batch[mid] < g) lo = mid+1; else hi = mid; }
    int s0 = lo;
    hi = N;
    while (lo < hi) { int mid = (lo+hi) >> 1; if (batch[mid] < g+1) lo = mid+1; else hi = mid; }
    int s1 = lo;

    int d2 = t & 63;
    float ax = 0.f, ay = 0.f;
    for (int row = s0 + (t >> 6); row < s1; row += 8) {
        unsigned int u = h2[(size_t)row*64 + d2];
        ax += bf2f((unsigned short)(u & 0xFFFFu));
        ay += bf2f((unsigned short)(u >> 16));
    }
    __shared__ float ps[128];
    if (t < 128) ps[t] = 0.f;
    __syncthreads();
    atomicAdd(&ps[2*d2],   ax);
    atomicAdd(&ps[2*d2+1], ay);
    __syncthreads();
    if (t < C) {
        float inv = 1.f / fmaxf((float)(s1 - s0), 1.f);
        float s = 0.f;
        #pragma unroll 4
        for (int k = 0; k < 128; ++k) s += ps[k] * fw[(size_t)k*C + t];
        out[(size_t)g*C + t] = s * inv + fb[t];
    }
}

extern "C" void kernel_launch(void* const* d_in, const int* in_sizes, int n_in,
                              void* d_out, int out_size, void* d_ws, size_t ws_size,
                              hipStream_t stream) {
    const float* x       = (const float*)d_in[0];
    const int*   eindex  = (const int*)  d_in[1];
    const int*   etype   = (const int*)  d_in[2];
    const int*   batch   = (const int*)  d_in[4];
    const float* basis   = (const float*)d_in[6];
    const float* comp    = (const float*)d_in[7];
    const float* root    = (const float*)d_in[8];
    const float* bias    = (const float*)d_in[9];
    const float* fc_w    = (const float*)d_in[10];
    const float* fc_b    = (const float*)d_in[11];

    int N  = in_sizes[4];          // 50000
    int E  = in_sizes[2];          // 600000
    int C  = in_sizes[11];         // 16
    int G  = out_size / C;         // 64
    int IO = in_sizes[8];          // 16384
    int B  = in_sizes[6] / IO;     // 4
    int R  = in_sizes[7] / B;      // 8
    int NR = N * R;
    int MB = ceil_div(N, 64);      // 64-row GEMM blocks
    int Mpad = MB * 64;

    const int* src = eindex;
    const int* dst = eindex + E;

    // ---- workspace layout (~134 MB) ----
    char* base = (char*)d_ws;
    size_t off = 0;
    auto alloc = [&](size_t bytes) -> char* {
        char* p = base + off;
        off = align_up(off + bytes, 256);
        return p;
    };
    unsigned short* Bt  = (unsigned short*)alloc(sizeof(unsigned short)*128*1152);
    int*   cnt      = (int*)  alloc(sizeof(int)*(size_t)NR);
    int*   offsets  = (int*)  alloc(sizeof(int)*((size_t)NR+1));
    int*   bsums    = (int*)  alloc(sizeof(int)*1024);
    int*   slot_src = (int*)  alloc(sizeof(int)*(size_t)E);
    unsigned short* h  = (unsigned short*)alloc(sizeof(unsigned short)*(size_t)Mpad*128);
    unsigned short* Xb = (unsigned short*)alloc(sizeof(unsigned short)*(size_t)Mpad*128);
    unsigned short* Mc = (unsigned short*)alloc(sizeof(unsigned short)*(size_t)Mpad*1024);

    // ---- pipeline ----
    hipMemsetAsync(cnt, 0, sizeof(int)*(size_t)NR, stream);
    compute_Bt_kernel<<<ceil_div(128*1152,256),256,0,stream>>>(comp, basis, root, Bt, B);
    count_kernel<<<ceil_div(E,256),256,0,stream>>>(dst, etype, cnt, E, R);

    int nb = ceil_div(NR, 1024);
    scan_block_kernel<<<nb,256,0,stream>>>(cnt, offsets, bsums, NR);
    scan_block_kernel<<<1,256,0,stream>>>(bsums, bsums, nullptr, nb);
    scan_add_kernel<<<ceil_div(NR,256),256,0,stream>>>(offsets, bsums, NR, E);

    fill_kernel<<<ceil_div(E,256),256,0,stream>>>(src, dst, etype, offsets, slot_src, E, R);

    xb_kernel<<<ceil_div(N*64,256),256,0,stream>>>(x, (unsigned int*)Xb, N);
    aggregate_kernel<<<ceil_div(N*64,256),256,0,stream>>>(offsets, slot_src,
                                                          (const unsigned int*)Xb,
                                                          (unsigned int*)Mc, N);

    mfma_gemm_kernel<<<MB,256,0,stream>>>(Mc, Xb, Bt, bias, h);

    pool_fc_kernel<<<G,512,0,stream>>>((const unsigned int*)h, batch, fc_w, fc_b,
                                       (float*)d_out, N, C);
}

// Round 7
// 215.136 us; speedup vs baseline: 1.4068x; 1.3217x over previous
//
#include <hip/hip_runtime.h>

static inline int ceil_div(int a, int b){ return (a+b-1)/b; }
static inline size_t align_up(size_t x, size_t a){ return (x + a - 1) / a * a; }

typedef __bf16 bf16x8 __attribute__((ext_vector_type(8)));
typedef float  f32x4  __attribute__((ext_vector_type(4)));

static __device__ inline unsigned short f2bf(float f){
    unsigned int u = __float_as_uint(f);
    unsigned int lsb = (u >> 16) & 1u;
    u += 0x7FFFu + lsb;
    return (unsigned short)(u >> 16);
}
static __device__ inline float bf2f(unsigned short b){
    return __uint_as_float(((unsigned int)b) << 16);
}
static __device__ inline unsigned int packbf(float a, float b){
    return (unsigned int)f2bf(a) | ((unsigned int)f2bf(b) << 16);
}

// async 16B global->LDS (wave-uniform LDS base + lane*16 layout)
static __device__ inline void gload_lds16(const void* g, void* l) {
    __builtin_amdgcn_global_load_lds(
        (const __attribute__((address_space(1))) unsigned int*)g,
        (__attribute__((address_space(3))) unsigned int*)l, 16, 0, 0);
}

// Bt[o][kk] bf16: kk<1024 -> W[r=kk>>7][i=kk&127][o]; kk>=1024 -> root[kk-1024][o]
__global__ void compute_Bt_kernel(const float* __restrict__ comp, const float* __restrict__ basis,
                                  const float* __restrict__ root, unsigned short* __restrict__ Bt,
                                  int B) {
    int idx = blockIdx.x*blockDim.x + threadIdx.x;
    if (idx >= 128*1152) return;
    int o = idx / 1152, kk = idx - o*1152;
    float val;
    if (kk < 1024) {
        int r = kk >> 7, i = kk & 127;
        val = 0.f;
        for (int b = 0; b < B; ++b)
            val += comp[r*B+b] * basis[((size_t)b*128 + i)*128 + o];
    } else {
        val = root[(size_t)(kk-1024)*128 + o];
    }
    Bt[idx] = f2bf(val);
}

__global__ void count_kernel(const int* __restrict__ dst, const int* __restrict__ et,
                             int* __restrict__ cnt, int E, int R) {
    int e = blockIdx.x*blockDim.x + threadIdx.x;
    if (e >= E) return;
    atomicAdd(&cnt[(size_t)dst[e]*R + et[e]], 1);
}

__global__ __launch_bounds__(256)
void scan_block_kernel(const int* __restrict__ in, int* __restrict__ out,
                       int* __restrict__ bsums, int n) {
    __shared__ int tsum[256];
    int t = threadIdx.x;
    int idx0 = blockIdx.x*1024 + t*4;
    int v0 = (idx0+0 < n) ? in[idx0+0] : 0;
    int v1 = (idx0+1 < n) ? in[idx0+1] : 0;
    int v2 = (idx0+2 < n) ? in[idx0+2] : 0;
    int v3 = (idx0+3 < n) ? in[idx0+3] : 0;
    int s = v0+v1+v2+v3;
    tsum[t] = s; __syncthreads();
    for (int off = 1; off < 256; off <<= 1) {
        int x = (t >= off) ? tsum[t-off] : 0;
        __syncthreads();
        tsum[t] += x;
        __syncthreads();
    }
    int run = tsum[t] - s;
    if (idx0+0 < n) out[idx0+0] = run; run += v0;
    if (idx0+1 < n) out[idx0+1] = run; run += v1;
    if (idx0+2 < n) out[idx0+2] = run; run += v2;
    if (idx0+3 < n) out[idx0+3] = run;
    if (bsums && t == 255) bsums[blockIdx.x] = tsum[255];
}

__global__ void scan_add_kernel(int* __restrict__ out, const int* __restrict__ bs,
                                int n, int total) {
    int i = blockIdx.x*blockDim.x + threadIdx.x;
    if (i < n) out[i] += bs[i >> 10];
    if (i == 0) out[n] = total;
}

// slot = atomicAdd(&offsets[bin],1): offsets mutates into shifted-by-one bounds.
__global__ void fill_kernel(const int* __restrict__ src, const int* __restrict__ dst,
                            const int* __restrict__ et, int* __restrict__ offsets,
                            int* __restrict__ slot_src, int E, int R) {
    int e = blockIdx.x*blockDim.x + threadIdx.x;
    if (e >= E) return;
    int bin = dst[e]*R + et[e];
    int slot = atomicAdd(&offsets[bin], 1);
    slot_src[slot] = src[e];
}

// x (f32) -> compact bf16 buffer Xb [N][128] (u32 pairs)
__global__ __launch_bounds__(256)
void xb_kernel(const float* __restrict__ x, unsigned int* __restrict__ Xb2, int N) {
    int t = blockIdx.x*blockDim.x + threadIdx.x;
    int n = t >> 6;
    if (n >= N) return;
    int l = t & 63;
    float2 v = reinterpret_cast<const float2*>(x + (size_t)n*128)[l];
    Xb2[(size_t)n*64 + l] = packbf(v.x, v.y);
}

// 4 waves per node, 2 bins per wave. Bounds shifted-by-one: bin b = [off[b-1], off[b]).
__global__ __launch_bounds__(256)
void aggregate_kernel(const int* __restrict__ offsets, const int* __restrict__ slot_src,
                      const unsigned int* __restrict__ Xb2, unsigned int* __restrict__ Mc2,
                      int N) {
    int gw = (int)((blockIdx.x*blockDim.x + threadIdx.x) >> 6);
    int node = gw >> 2, part = gw & 3;
    if (node >= N) return;
    int l = threadIdx.x & 63;
    int base = node*8 + part*2;
    int lo   = (base == 0) ? 0 : offsets[base-1];
    int bmid = offsets[base];
    int hi   = offsets[base+1];

    float ax0=0.f, ay0=0.f, ax1=0.f, ay1=0.f;

#define ACC2(E_, U_) { \
    float vx_ = bf2f((unsigned short)((U_) & 0xFFFFu)); \
    float vy_ = bf2f((unsigned short)((U_) >> 16)); \
    if ((E_) < bmid) { ax0 += vx_; ay0 += vy_; } \
    else             { ax1 += vx_; ay1 += vy_; } }

    int e = lo;
    for (; e + 4 <= hi; e += 4) {
        int s0 = slot_src[e], s1 = slot_src[e+1], s2 = slot_src[e+2], s3 = slot_src[e+3];
        unsigned int u0 = Xb2[(size_t)s0*64 + l];
        unsigned int u1 = Xb2[(size_t)s1*64 + l];
        unsigned int u2 = Xb2[(size_t)s2*64 + l];
        unsigned int u3 = Xb2[(size_t)s3*64 + l];
        ACC2(e+0, u0) ACC2(e+1, u1) ACC2(e+2, u2) ACC2(e+3, u3)
    }
    for (; e < hi; ++e) {
        int s = slot_src[e];
        unsigned int u = Xb2[(size_t)s*64 + l];
        ACC2(e, u)
    }
#undef ACC2

    unsigned int* Mrow = Mc2 + (size_t)node*512;
    float i0 = 1.f/fmaxf((float)(bmid-lo), 1.f);
    float i1 = 1.f/fmaxf((float)(hi-bmid), 1.f);
    Mrow[(2*part+0)*64 + l] = packbf(ax0*i0, ay0*i0);
    Mrow[(2*part+1)*64 + l] = packbf(ax1*i1, ay1*i1);
}

// h(bf16)[Mpad][128] = relu( [Mc | Xb] @ Bt^T + bias )
// m97-style: BM=64 x BN=128 tile, BK=64, single-buffered LDS, global_load_lds(16B),
// XOR-swizzled source+read (linear LDS dest). 4 waves: rg=wid&1 (32 rows), cg=wid>>1 (64 cols).
__global__ __launch_bounds__(256)
void mfma_gemm_kernel(const unsigned short* __restrict__ Mc,
                      const unsigned short* __restrict__ Xb,
                      const unsigned short* __restrict__ Btc,
                      const float* __restrict__ bias,
                      unsigned short* __restrict__ h) {
    __shared__ char ldsA[64*128];    // 8 KB:  64 rows x 128 B (this chunk's 64 k)
    __shared__ char ldsB[128*128];   // 16 KB: 128 cols x 128 B

    int tid  = threadIdx.x;
    int lane = tid & 63;
    int wid  = tid >> 6;
    int rg = wid & 1, cg = wid >> 1;
    int fr = lane & 15, kb = lane >> 4;
    long m0 = (long)blockIdx.x * 64;

    int lrow8 = lane >> 3;            // 0..7 row within an issue
    int lcb   = (lane & 7) * 16;      // 16B slot within 128B row

    f32x4 acc[2][4];
    #pragma unroll
    for (int mf = 0; mf < 2; ++mf)
        #pragma unroll
        for (int nf = 0; nf < 4; ++nf) acc[mf][nf] = f32x4{0.f,0.f,0.f,0.f};

    const char* McB = (const char*)Mc;
    const char* XbB = (const char*)Xb;
    const char* BtB = (const char*)Btc;

    for (int t = 0; t < 18; ++t) {
        // ---- stage chunk t: A (2 issues/wave), B (4 issues/wave) ----
        #pragma unroll
        for (int i = 0; i < 2; ++i) {
            int row = wid*16 + i*8 + lrow8;
            int sw  = lcb ^ ((row & 7) << 4);
            const char* g = (t < 16)
                ? McB + (size_t)(m0 + row)*2048 + t*128 + sw
                : XbB + (size_t)(m0 + row)*256 + (t-16)*128 + sw;
            gload_lds16(g, &ldsA[wid*2048 + i*1024 + lane*16]);
        }
        #pragma unroll
        for (int i = 0; i < 4; ++i) {
            int col = wid*32 + i*8 + lrow8;
            int sw  = lcb ^ ((col & 7) << 4);
            const char* g = BtB + (size_t)col*2304 + t*128 + sw;
            gload_lds16(g, &ldsB[wid*4096 + i*1024 + lane*16]);
        }
        __syncthreads();   // drains vmcnt -> LDS tile complete

        // ---- compute: 12 ds_read_b128 + 16 MFMA ----
        bf16x8 af[2][2], bf[4][2];
        #pragma unroll
        for (int mf = 0; mf < 2; ++mf) {
            int row = rg*32 + mf*16 + fr;
            #pragma unroll
            for (int kk = 0; kk < 2; ++kk) {
                int byte = row*128 + ((kk*64 + kb*16) ^ ((row & 7) << 4));
                af[mf][kk] = *reinterpret_cast<const bf16x8*>(&ldsA[byte]);
            }
        }
        #pragma unroll
        for (int nf = 0; nf < 4; ++nf) {
            int col = cg*64 + nf*16 + fr;
            #pragma unroll
            for (int kk = 0; kk < 2; ++kk) {
                int byte = col*128 + ((kk*64 + kb*16) ^ ((col & 7) << 4));
                bf[nf][kk] = *reinterpret_cast<const bf16x8*>(&ldsB[byte]);
            }
        }
        #pragma unroll
        for (int kk = 0; kk < 2; ++kk)
            #pragma unroll
            for (int mf = 0; mf < 2; ++mf)
                #pragma unroll
                for (int nf = 0; nf < 4; ++nf)
                    acc[mf][nf] = __builtin_amdgcn_mfma_f32_16x16x32_bf16(
                        af[mf][kk], bf[nf][kk], acc[mf][nf], 0, 0, 0);
        __syncthreads();   // buffer safe to overwrite
    }

    float bb[4];
    #pragma unroll
    for (int nf = 0; nf < 4; ++nf) bb[nf] = bias[cg*64 + nf*16 + fr];

    #pragma unroll
    for (int mf = 0; mf < 2; ++mf)
        #pragma unroll
        for (int q = 0; q < 4; ++q) {
            long r = m0 + rg*32 + mf*16 + kb*4 + q;
            unsigned short* hr = h + (size_t)r*128 + cg*64;
            #pragma unroll
            for (int nf = 0; nf < 4; ++nf)
                hr[nf*16 + fr] = f2bf(fmaxf(acc[mf][nf][q] + bb[nf], 0.f));
        }
}

// Fused: per-graph row-range (binary search on sorted batch) -> mean pool -> FC.
__global__ __launch_bounds__(512)
void pool_fc_kernel(const unsigned int* __restrict__ h2, const int* __restrict__ batch,
                    const float* __restrict__ fw, const float* __restrict__ fb,
                    float* __restrict__ out, int N, int C) {
    int g = blockIdx.x;
    int t = threadIdx.x;
    int lo = 0, hi = N;
    while (lo < hi) { int mid = (lo+hi) >> 1; if (batch[mid] < g) lo = mid+1; else hi = mid; }
    int s0 = lo;
    hi = N;
    while (lo < hi) { int mid = (lo+hi) >> 1; if (batch[mid] < g+1) lo = mid+1; else hi = mid; }
    int s1 = lo;

    int d2 = t & 63;
    float ax = 0.f, ay = 0.f;
    for (int row = s0 + (t >> 6); row < s1; row += 8) {
        unsigned int u = h2[(size_t)row*64 + d2];
        ax += bf2f((unsigned short)(u & 0xFFFFu));
        ay += bf2f((unsigned short)(u >> 16));
    }
    __shared__ float ps[128];
    if (t < 128) ps[t] = 0.f;
    __syncthreads();
    atomicAdd(&ps[2*d2],   ax);
    atomicAdd(&ps[2*d2+1], ay);
    __syncthreads();
    if (t < C) {
        float inv = 1.f / fmaxf((float)(s1 - s0), 1.f);
        float s = 0.f;
        #pragma unroll 4
        for (int k = 0; k < 128; ++k) s += ps[k] * fw[(size_t)k*C + t];
        out[(size_t)g*C + t] = s * inv + fb[t];
    }
}

extern "C" void kernel_launch(void* const* d_in, const int* in_sizes, int n_in,
                              void* d_out, int out_size, void* d_ws, size_t ws_size,
                              hipStream_t stream) {
    const float* x       = (const float*)d_in[0];
    const int*   eindex  = (const int*)  d_in[1];
    const int*   etype   = (const int*)  d_in[2];
    const int*   batch   = (const int*)  d_in[4];
    const float* basis   = (const float*)d_in[6];
    const float* comp    = (const float*)d_in[7];
    const float* root    = (const float*)d_in[8];
    const float* bias    = (const float*)d_in[9];
    const float* fc_w    = (const float*)d_in[10];
    const float* fc_b    = (const float*)d_in[11];

    int N  = in_sizes[4];          // 50000
    int E  = in_sizes[2];          // 600000
    int C  = in_sizes[11];         // 16
    int G  = out_size / C;         // 64
    int IO = in_sizes[8];          // 16384
    int B  = in_sizes[6] / IO;     // 4
    int R  = in_sizes[7] / B;      // 8
    int NR = N * R;
    int MB = ceil_div(N, 64);      // 64-row GEMM blocks
    int Mpad = MB * 64;

    const int* src = eindex;
    const int* dst = eindex + E;

    // ---- workspace layout (~134 MB) ----
    char* base = (char*)d_ws;
    size_t off = 0;
    auto alloc = [&](size_t bytes) -> char* {
        char* p = base + off;
        off = align_up(off + bytes, 256);
        return p;
    };
    unsigned short* Bt  = (unsigned short*)alloc(sizeof(unsigned short)*128*1152);
    int*   cnt      = (int*)  alloc(sizeof(int)*(size_t)NR);
    int*   offsets  = (int*)  alloc(sizeof(int)*((size_t)NR+1));
    int*   bsums    = (int*)  alloc(sizeof(int)*1024);
    int*   slot_src = (int*)  alloc(sizeof(int)*(size_t)E);
    unsigned short* h  = (unsigned short*)alloc(sizeof(unsigned short)*(size_t)Mpad*128);
    unsigned short* Xb = (unsigned short*)alloc(sizeof(unsigned short)*(size_t)Mpad*128);
    unsigned short* Mc = (unsigned short*)alloc(sizeof(unsigned short)*(size_t)Mpad*1024);

    // ---- pipeline ----
    hipMemsetAsync(cnt, 0, sizeof(int)*(size_t)NR, stream);
    compute_Bt_kernel<<<ceil_div(128*1152,256),256,0,stream>>>(comp, basis, root, Bt, B);
    count_kernel<<<ceil_div(E,256),256,0,stream>>>(dst, etype, cnt, E, R);

    int nb = ceil_div(NR, 1024);
    scan_block_kernel<<<nb,256,0,stream>>>(cnt, offsets, bsums, NR);
    scan_block_kernel<<<1,256,0,stream>>>(bsums, bsums, nullptr, nb);
    scan_add_kernel<<<ceil_div(NR,256),256,0,stream>>>(offsets, bsums, NR, E);

    fill_kernel<<<ceil_div(E,256),256,0,stream>>>(src, dst, etype, offsets, slot_src, E, R);

    xb_kernel<<<ceil_div(N*64,256),256,0,stream>>>(x, (unsigned int*)Xb, N);
    aggregate_kernel<<<ceil_div(N*4*64,256),256,0,stream>>>(offsets, slot_src,
                                                            (const unsigned int*)Xb,
                                                            (unsigned int*)Mc, N);

    mfma_gemm_kernel<<<MB,256,0,stream>>>(Mc, Xb, Bt, bias, h);

    pool_fc_kernel<<<G,512,0,stream>>>((const unsigned int*)h, batch, fc_w, fc_b,
                                       (float*)d_out, N, C);
}